// Round 1
// baseline (197.837 us; speedup 1.0000x reference)
//
#include <hip/hip_runtime.h>
#include <stdint.h>

// Problem geometry (fixed by the reference):
//   inputs: [1024] f32  -> 32768 bits (bit c = (u[c>>5] >> ((c&31)^7)) & 1)
//   W_hat, M_hat: [4096, 32768] f32
//   binary_outputs[r] = sum_c tanh(W[r,c])*sigmoid(M[r,c]) * bit[c]   (GEMV)
//   out[i] = bitcast(sum_j clip(round(bo[i*32+j]),0,1) << (j^7)), i in [0,128)
//
// Memory-bound: must stream 1.074 GB (both matrices) exactly once.
// Roofline @6.3 TB/s achievable => ~170 us.

#define IN_N   1024
#define INB    32768
#define OUTB   4096
#define TPB    256
#define ITERS  (INB / (TPB * 4))   // 32 float4-iterations per thread

__global__ __launch_bounds__(TPB) void nac_gemv_kernel(
    const float* __restrict__ inp,
    const float* __restrict__ Wh,
    const float* __restrict__ Mh,
    float* __restrict__ bo)   // [OUTB] row sums
{
  __shared__ uint32_t ub[IN_N];
  const int tid = threadIdx.x;

  // Stage the 1024 input words (4 KB) into LDS; served from L2 after block 0.
  for (int i = tid; i < IN_N; i += TPB)
    ub[i] = __float_as_uint(inp[i]);
  __syncthreads();

  // Pre-pack this thread's 128 bits into 4 registers:
  //   bit 'it' of pk[k] = bit of column c = it*1024 + tid*4 + k.
  // c>>5 = it*32 + (tid*4)>>5 (k never crosses a word: tid*4 is 4-aligned).
  // shift = ((tid*4+k)&31)^7 = s0 - k  where s0 = ((tid*4)&31)^7.
  const int wof = (tid * 4) >> 5;
  const int s0  = ((tid * 4) & 31) ^ 7;
  uint32_t pk0 = 0, pk1 = 0, pk2 = 0, pk3 = 0;
  #pragma unroll
  for (int it = 0; it < ITERS; ++it) {
    const uint32_t u = ub[it * 32 + wof];
    pk0 |= ((u >> (s0 - 0)) & 1u) << it;
    pk1 |= ((u >> (s0 - 1)) & 1u) << it;
    pk2 |= ((u >> (s0 - 2)) & 1u) << it;
    pk3 |= ((u >> (s0 - 3)) & 1u) << it;
  }

  const int row = blockIdx.x;
  const float4* __restrict__ W4 = (const float4*)(Wh + (size_t)row * INB);
  const float4* __restrict__ M4 = (const float4*)(Mh + (size_t)row * INB);

  float acc = 0.0f;
  #pragma unroll 4
  for (int it = 0; it < ITERS; ++it) {
    const float4 w = W4[it * TPB + tid];   // coalesced 16 B/lane
    const float4 m = M4[it * TPB + tid];
    const float wv[4] = {w.x, w.y, w.z, w.w};
    const float mv[4] = {m.x, m.y, m.z, m.w};
    const uint32_t bits[4] = {(pk0 >> it) & 1u, (pk1 >> it) & 1u,
                              (pk2 >> it) & 1u, (pk3 >> it) & 1u};
    #pragma unroll
    for (int k = 0; k < 4; ++k) {
      // tanh(x) = 2/(1+exp(-2x)) - 1 ; sigmoid(x) = 1/(1+exp(-x))
      const float t = 2.0f / (1.0f + __expf(-2.0f * wv[k])) - 1.0f;
      const float s = 1.0f / (1.0f + __expf(-mv[k]));
      const float v = t * s;
      acc += bits[k] ? v : 0.0f;
    }
  }

  // Block reduction: wave shuffle then LDS across the 4 waves.
  #pragma unroll
  for (int off = 32; off > 0; off >>= 1)
    acc += __shfl_down(acc, off, 64);

  __shared__ float red[TPB / 64];
  if ((tid & 63) == 0) red[tid >> 6] = acc;
  __syncthreads();
  if (tid == 0)
    bo[row] = (red[0] + red[1]) + (red[2] + red[3]);
}

__global__ void unbin_kernel(const float* __restrict__ bo,
                             float* __restrict__ out)
{
  const int i = blockIdx.x * blockDim.x + threadIdx.x;
  if (i >= OUTB / 32) return;
  uint32_t u = 0;
  #pragma unroll
  for (int j = 0; j < 32; ++j) {
    float x = rintf(bo[i * 32 + j]);          // round half-to-even (matches jnp.round)
    x = fminf(fmaxf(x, 0.0f), 1.0f);          // clip AFTER round
    u |= ((uint32_t)x) << (j ^ 7);
  }
  out[i] = __uint_as_float(u);
}

extern "C" void kernel_launch(void* const* d_in, const int* in_sizes, int n_in,
                              void* d_out, int out_size, void* d_ws, size_t ws_size,
                              hipStream_t stream) {
  const float* inp = (const float*)d_in[0];   // [1024]
  const float* Wh  = (const float*)d_in[1];   // [4096*32768]
  const float* Mh  = (const float*)d_in[2];   // [4096*32768]
  float* out = (float*)d_out;                 // [128]
  float* bo  = (float*)d_ws;                  // [4096] scratch row sums

  nac_gemv_kernel<<<OUTB, TPB, 0, stream>>>(inp, Wh, Mh, bo);
  unbin_kernel<<<1, 128, 0, stream>>>(bo, out);
}

// Round 2
// 164.365 us; speedup vs baseline: 1.2036x; 1.2036x over previous
//
#include <hip/hip_runtime.h>
#include <stdint.h>

// Problem geometry (fixed by the reference):
//   inputs: [1024] f32  -> 32768 bits (bit c = (u[c>>5] >> ((c&31)^7)) & 1)
//   W_hat, M_hat: [4096, 32768] f32
//   binary_outputs[r] = sum_c tanh(W[r,c])*sigmoid(M[r,c]) * bit[c]   (GEMV)
//   out[i] = bitcast(sum_j clip(round(bo[i*32+j]),0,1) << (j^7)), i in [0,128)
//
// Memory-bound: must stream 1.074 GB (both matrices) exactly once.
// Chip streaming ceiling (observed via harness fill kernels): ~6.6 TB/s
// => floor ~165 us. R1 (div-based math): 198 us. This round: v_rcp math,
// nontemporal loads, split accumulators.

#define IN_N   1024
#define INB    32768
#define OUTB   4096
#define TPB    256
#define ITERS  (INB / (TPB * 4))   // 32 float4-iterations per thread

typedef float f4 __attribute__((ext_vector_type(4)));

__global__ __launch_bounds__(TPB) void nac_gemv_kernel(
    const float* __restrict__ inp,
    const float* __restrict__ Wh,
    const float* __restrict__ Mh,
    float* __restrict__ bo)   // [OUTB] row sums
{
  __shared__ uint32_t ub[IN_N];
  const int tid = threadIdx.x;

  // Stage the 1024 input words (4 KB) into LDS; served from L2 after block 0.
  for (int i = tid; i < IN_N; i += TPB)
    ub[i] = __float_as_uint(inp[i]);
  __syncthreads();

  // Pre-pack this thread's 128 bits into 4 registers:
  //   bit 'it' of pk[k] = bit of column c = it*1024 + tid*4 + k.
  // c>>5 = it*32 + (tid*4)>>5 (k never crosses a word: tid*4 is 4-aligned).
  // shift = ((tid*4+k)&31)^7 = s0 - k  where s0 = ((tid*4)&31)^7.
  const int wof = (tid * 4) >> 5;
  const int s0  = ((tid * 4) & 31) ^ 7;
  uint32_t pk0 = 0, pk1 = 0, pk2 = 0, pk3 = 0;
  #pragma unroll
  for (int it = 0; it < ITERS; ++it) {
    const uint32_t u = ub[it * 32 + wof];
    pk0 |= ((u >> (s0 - 0)) & 1u) << it;
    pk1 |= ((u >> (s0 - 1)) & 1u) << it;
    pk2 |= ((u >> (s0 - 2)) & 1u) << it;
    pk3 |= ((u >> (s0 - 3)) & 1u) << it;
  }

  const int row = blockIdx.x;
  const f4* __restrict__ W4 = (const f4*)(Wh + (size_t)row * INB);
  const f4* __restrict__ M4 = (const f4*)(Mh + (size_t)row * INB);

  float a0 = 0.0f, a1 = 0.0f, a2 = 0.0f, a3 = 0.0f;
  #pragma unroll 4
  for (int it = 0; it < ITERS; ++it) {
    const f4 w = __builtin_nontemporal_load(W4 + it * TPB + tid);  // 16 B/lane, streaming
    const f4 m = __builtin_nontemporal_load(M4 + it * TPB + tid);
    // tanh(x)*sigmoid(y) = (2/(1+exp(-2x)) - 1) * (1/(1+exp(-y)))
    // |x|,|y| <~ 0.15 here, so v_rcp_f32 (~1 ulp) is plenty.
    {
      const float r1 = __builtin_amdgcn_rcpf(1.0f + __expf(-2.0f * w.x));
      const float r2 = __builtin_amdgcn_rcpf(1.0f + __expf(-m.x));
      const float v  = fmaf(2.0f, r1, -1.0f) * r2;
      a0 += ((pk0 >> it) & 1u) ? v : 0.0f;
    }
    {
      const float r1 = __builtin_amdgcn_rcpf(1.0f + __expf(-2.0f * w.y));
      const float r2 = __builtin_amdgcn_rcpf(1.0f + __expf(-m.y));
      const float v  = fmaf(2.0f, r1, -1.0f) * r2;
      a1 += ((pk1 >> it) & 1u) ? v : 0.0f;
    }
    {
      const float r1 = __builtin_amdgcn_rcpf(1.0f + __expf(-2.0f * w.z));
      const float r2 = __builtin_amdgcn_rcpf(1.0f + __expf(-m.z));
      const float v  = fmaf(2.0f, r1, -1.0f) * r2;
      a2 += ((pk2 >> it) & 1u) ? v : 0.0f;
    }
    {
      const float r1 = __builtin_amdgcn_rcpf(1.0f + __expf(-2.0f * w.w));
      const float r2 = __builtin_amdgcn_rcpf(1.0f + __expf(-m.w));
      const float v  = fmaf(2.0f, r1, -1.0f) * r2;
      a3 += ((pk3 >> it) & 1u) ? v : 0.0f;
    }
  }
  float acc = (a0 + a1) + (a2 + a3);

  // Block reduction: wave shuffle then LDS across the 4 waves.
  #pragma unroll
  for (int off = 32; off > 0; off >>= 1)
    acc += __shfl_down(acc, off, 64);

  __shared__ float red[TPB / 64];
  if ((tid & 63) == 0) red[tid >> 6] = acc;
  __syncthreads();
  if (tid == 0)
    bo[row] = (red[0] + red[1]) + (red[2] + red[3]);
}

__global__ void unbin_kernel(const float* __restrict__ bo,
                             float* __restrict__ out)
{
  const int i = blockIdx.x * blockDim.x + threadIdx.x;
  if (i >= OUTB / 32) return;
  uint32_t u = 0;
  #pragma unroll
  for (int j = 0; j < 32; ++j) {
    float x = rintf(bo[i * 32 + j]);          // round half-to-even (matches jnp.round)
    x = fminf(fmaxf(x, 0.0f), 1.0f);          // clip AFTER round
    u |= ((uint32_t)x) << (j ^ 7);
  }
  out[i] = __uint_as_float(u);
}

extern "C" void kernel_launch(void* const* d_in, const int* in_sizes, int n_in,
                              void* d_out, int out_size, void* d_ws, size_t ws_size,
                              hipStream_t stream) {
  const float* inp = (const float*)d_in[0];   // [1024]
  const float* Wh  = (const float*)d_in[1];   // [4096*32768]
  const float* Mh  = (const float*)d_in[2];   // [4096*32768]
  float* out = (float*)d_out;                 // [128]
  float* bo  = (float*)d_ws;                  // [4096] scratch row sums

  nac_gemv_kernel<<<OUTB, TPB, 0, stream>>>(inp, Wh, Mh, bo);
  unbin_kernel<<<1, 128, 0, stream>>>(bo, out);
}